// Round 7
// baseline (100.436 us; speedup 1.0000x reference)
//
#include <hip/hip_runtime.h>

#define B_SZ 8192

// ---------------- masks (exact 1.5-entmax via bisection) + fused params ----------------
struct MaskArgs {
  const float* fm[6];
  const float* cp[6];
  const float* lr[6];
  float* out_masks;  // d_out base
  float4* prm;       // fused params {c10, ml0, ml1, 0}
  float* cstf;       // flat per-output 0.5*sum(ml): level d at 2*cstOff[d]
};

__device__ __forceinline__ float wave_max(float v) {
#pragma unroll
  for (int o = 32; o > 0; o >>= 1) v = fmaxf(v, __shfl_xor(v, o));
  return v;
}
__device__ __forceinline__ float wave_sum(float v) {
#pragma unroll
  for (int o = 32; o > 0; o >>= 1) v += __shfl_xor(v, o);
  return v;
}

__global__ __launch_bounds__(64) void ndt_masks(MaskArgs a) {
  const int maskOff[6] = {524288, 524544, 525060, 526100, 528212, 532564};
  const int prmOff[6]  = {0, 256, 772, 1812, 3924, 8276};
  const int cstOff[6]  = {0, 1, 3, 7, 15, 31};
  int bid = blockIdx.x, lane = threadIdx.x;
  int d = 0, s = bid, n = 1;
  while (s >= n) { s -= n; n <<= 1; ++d; }   // level d, stump s, n = 2^d
  int Fd = 256 + ((d > 0) ? n : 0);

  const float* fm = a.fm[d] + (size_t)s * Fd;
  float y[5];
#pragma unroll
  for (int j = 0; j < 5; ++j) {
    int f = lane + 64 * j;
    y[j] = (f < Fd) ? fm[f] * 0.5f : -3.0e38f;
  }
  float m = fmaxf(fmaxf(fmaxf(y[0], y[1]), fmaxf(y[2], y[3])), y[4]);
  m = wave_max(m);
#pragma unroll
  for (int j = 0; j < 5; ++j) y[j] -= m;

  // solve sum clip(y - tau, 0)^2 = 1 ; tau in [-1, 0], strictly decreasing in tau
  float lo = -1.f, hi = 0.f;
  for (int it = 0; it < 24; ++it) {
    float tau = 0.5f * (lo + hi);
    float ss = 0.f;
#pragma unroll
    for (int j = 0; j < 5; ++j) {
      float v = fmaxf(y[j] - tau, 0.f);
      ss = __builtin_fmaf(v, v, ss);
    }
    ss = wave_sum(ss);
    if (ss >= 1.f) lo = tau; else hi = tau;
  }
  float tau = 0.5f * (lo + hi);

  float* mo = a.out_masks + maskOff[d] + (size_t)s * Fd;
  const float* cp = a.cp[d] + (size_t)s * Fd * 2;
  const float* lr = a.lr[d] + (size_t)s * Fd * 2;
  float4* pr = a.prm + prmOff[d] + (size_t)s * Fd;
  float sum0 = 0.f, sum1 = 0.f;
#pragma unroll
  for (int j = 0; j < 5; ++j) {
    int f = lane + 64 * j;
    if (f < Fd) {
      float v = fmaxf(y[j] - tau, 0.f);
      float mk = v * v;
      mo[f] = mk;
      float c0 = cp[2 * f], c1 = cp[2 * f + 1];
      float ml0 = lr[2 * f] * mk, ml1 = lr[2 * f + 1] * mk;
      sum0 += ml0;
      sum1 += ml1;
      pr[f] = make_float4(c1 - c0, ml0, ml1, 0.f);
    }
  }
  sum0 = wave_sum(sum0);
  sum1 = wave_sum(sum1);
  if (lane == 0) {
    a.cstf[2 * (cstOff[d] + s)] = 0.5f * sum0;
    a.cstf[2 * (cstOff[d] + s) + 1] = 0.5f * sum1;
  }
}

// 2-elem entmax15 closed form: t = c10 - x; tc = clamp(t,-2,2);
// e = tc*sqrt(0.125 - tc^2/64); p0 = 0.5+e, p1 = 0.5-e.
__device__ __forceinline__ float entpair(float c10, float xv) {
  float t = c10 - xv;
  float tc = __builtin_amdgcn_fmed3f(t, -2.f, 2.f);
  float u = __builtin_fmaf(tc * tc, -0.015625f, 0.125f);
  return tc * __builtin_amdgcn_sqrtf(u);
}

// ---------------- levels 0-2 fused: 32-row blocks, 8 groups x 32 lanes ----------------
__global__ __launch_bounds__(256) void ndt_l012(const float* __restrict__ x,
                                                const float4* __restrict__ prm,
                                                const float* __restrict__ cstf,
                                                float* __restrict__ out2) {
  __shared__ float xls[256 * 32];
  __shared__ float4 pl[1812];
  __shared__ float pbuf[8][2][32];
  int tid = threadIdx.x;
  int r = tid & 31, c = tid >> 5;
  int b0 = blockIdx.x * 32;
  for (int i = tid; i < 1812; i += 256) pl[i] = prm[i];
  {
    const float4* xp = (const float4*)(x + (size_t)(b0 + r) * 256 + c * 32);
#pragma unroll
    for (int j = 0; j < 8; ++j) {
      float4 g = xp[j];
      int f = c * 32 + 4 * j;
      xls[(f + 0) * 32 + (r ^ ((4 * j + 0) & 31))] = g.x;
      xls[(f + 1) * 32 + (r ^ ((4 * j + 1) & 31))] = g.y;
      xls[(f + 2) * 32 + (r ^ ((4 * j + 2) & 31))] = g.z;
      xls[(f + 3) * 32 + (r ^ ((4 * j + 3) & 31))] = g.w;
    }
  }
  __syncthreads();
  // ---- L0: group c -> features [c*32, c*32+32)
  float a0 = 0.f, a1 = 0.f;
#pragma unroll
  for (int j = 0; j < 32; ++j) {
    int f = c * 32 + j;
    float xv = xls[f * 32 + (r ^ j)];
    float4 p = pl[f];
    float e = entpair(p.x, xv);
    a0 = __builtin_fmaf(e, p.y, a0);
    a1 = __builtin_fmaf(-e, p.z, a1);
  }
  pbuf[c][0][r] = a0;
  pbuf[c][1][r] = a1;
  __syncthreads();
  float xe1[2];
#pragma unroll
  for (int o = 0; o < 2; ++o) {
    float v = cstf[o];
#pragma unroll
    for (int k = 0; k < 8; ++k) v += pbuf[k][o][r];
    xe1[o] = v;
  }
  __syncthreads();
  // ---- L1: stump c>>2, feature slice (c&3)*64; extras on slice 0
  {
    int s = c >> 2, fs = c & 3;
    const float4* ps = &pl[256 + s * 258];
    a0 = 0.f;
    a1 = 0.f;
#pragma unroll
    for (int j = 0; j < 64; ++j) {
      int f = fs * 64 + j;
      float xv = xls[f * 32 + (r ^ (f & 31))];
      float4 p = ps[f];
      float e = entpair(p.x, xv);
      a0 = __builtin_fmaf(e, p.y, a0);
      a1 = __builtin_fmaf(-e, p.z, a1);
    }
    if (fs == 0) {
#pragma unroll
      for (int o = 0; o < 2; ++o) {
        float4 p = ps[256 + o];
        float e = entpair(p.x, xe1[o]);
        a0 = __builtin_fmaf(e, p.y, a0);
        a1 = __builtin_fmaf(-e, p.z, a1);
      }
    }
    pbuf[c][0][r] = a0;
    pbuf[c][1][r] = a1;
  }
  __syncthreads();
  float xe2[4];
#pragma unroll
  for (int s = 0; s < 2; ++s)
#pragma unroll
    for (int o = 0; o < 2; ++o) {
      float v = cstf[2 + 2 * s + o];
#pragma unroll
      for (int k = 0; k < 4; ++k) v += pbuf[4 * s + k][o][r];
      xe2[2 * s + o] = v;
    }
  __syncthreads();
  // ---- L2: stump c>>1, feature slice (c&1)*128; extras on slice 0
  {
    int s = c >> 1, fs = c & 1;
    const float4* ps = &pl[772 + s * 260];
    a0 = 0.f;
    a1 = 0.f;
#pragma unroll
    for (int j = 0; j < 128; ++j) {
      int f = fs * 128 + j;
      float xv = xls[f * 32 + (r ^ (f & 31))];
      float4 p = ps[f];
      float e = entpair(p.x, xv);
      a0 = __builtin_fmaf(e, p.y, a0);
      a1 = __builtin_fmaf(-e, p.z, a1);
    }
    if (fs == 0) {
#pragma unroll
      for (int o = 0; o < 4; ++o) {
        float4 p = ps[256 + o];
        float e = entpair(p.x, xe2[o]);
        a0 = __builtin_fmaf(e, p.y, a0);
        a1 = __builtin_fmaf(-e, p.z, a1);
      }
    }
    pbuf[c][0][r] = a0;
    pbuf[c][1][r] = a1;
  }
  __syncthreads();
  // ---- reduce L2 -> out2[row][8]; groups 0/1 write float4 halves
  if (c < 2) {
    float o4[4];
#pragma unroll
    for (int i = 0; i < 4; ++i) {
      int s = 2 * c + (i >> 1), o = i & 1;
      float v = cstf[6 + 2 * s + o];
#pragma unroll
      for (int k = 0; k < 2; ++k) v += pbuf[2 * s + k][o][r];
      o4[i] = v;
    }
    *(float4*)(out2 + (size_t)(b0 + r) * 8 + 4 * c) =
        make_float4(o4[0], o4[1], o4[2], o4[3]);
  }
}

// ---------------- big levels (3,4,5): thread <-> row, params in LDS ----------
// 1-D grid of 32*G blocks, XCD-swizzled: all G stump-group blocks of row-block rb
// land on XCD rb%8 (blockIdx%8 -> XCD round-robin), so each XCD re-reads only its
// 1 MB x slice from its own L2 instead of 8 MB * G from L3.
// Params in LDS (wave-uniform broadcast b128); x streamed from global (L2-resident).
template <int EX, int NSW, int G>
__global__ __launch_bounds__(256, 4) void ndt_big(const float* __restrict__ x,
                                                  const float* __restrict__ prev,
                                                  const float4* __restrict__ prmL,
                                                  const float* __restrict__ cstL,
                                                  float* __restrict__ outp,
                                                  int outStride) {
  constexpr int FD = 256 + EX;
  __shared__ float4 pl[NSW * FD];
  int tid = threadIdx.x;
  int b = blockIdx.x;
  int xcd = b & 7, t = b >> 3;
  int g = t % G, rq = t / G;
  int rb = xcd + 8 * rq;  // row-block in [0,32)
  int s0 = g * NSW;
  for (int i = tid; i < NSW * FD; i += 256) pl[i] = prmL[(size_t)s0 * FD + i];

  int row = rb * 256 + tid;
  // prev-level outputs of this row -> registers
  float pv[EX];
  {
    const float4* pvp = (const float4*)(prev + (size_t)row * EX);
#pragma unroll
    for (int k = 0; k < EX / 4; ++k) {
      float4 v = pvp[k];
      pv[4 * k] = v.x;
      pv[4 * k + 1] = v.y;
      pv[4 * k + 2] = v.z;
      pv[4 * k + 3] = v.w;
    }
  }
  __syncthreads();

  float acc[2 * NSW];
#pragma unroll
  for (int i = 0; i < 2 * NSW; ++i) acc[i] = 0.f;

  const float4* xp = (const float4*)(x + (size_t)row * 256);
#pragma unroll 2
  for (int gg = 0; gg < 16; ++gg) {
    float4 xq[4];
#pragma unroll
    for (int q = 0; q < 4; ++q) xq[q] = xp[4 * gg + q];
#pragma unroll
    for (int q = 0; q < 4; ++q) {
      float xa[4] = {xq[q].x, xq[q].y, xq[q].z, xq[q].w};
#pragma unroll
      for (int i = 0; i < 4; ++i) {
#pragma unroll
        for (int s = 0; s < NSW; ++s) {
          float4 p = pl[s * FD + 16 * gg + 4 * q + i];  // uniform -> broadcast
          float e = entpair(p.x, xa[i]);
          acc[2 * s] = __builtin_fmaf(e, p.y, acc[2 * s]);
          acc[2 * s + 1] = __builtin_fmaf(-e, p.z, acc[2 * s + 1]);
        }
      }
    }
  }
  // tail: extra features = prev outputs (registers)
#pragma unroll
  for (int o = 0; o < EX; ++o) {
#pragma unroll
    for (int s = 0; s < NSW; ++s) {
      float4 p = pl[s * FD + 256 + o];
      float e = entpair(p.x, pv[o]);
      acc[2 * s] = __builtin_fmaf(e, p.y, acc[2 * s]);
      acc[2 * s + 1] = __builtin_fmaf(-e, p.z, acc[2 * s + 1]);
    }
  }
#pragma unroll
  for (int s = 0; s < NSW; ++s) {
    acc[2 * s] += cstL[2 * (s0 + s)];
    acc[2 * s + 1] += cstL[2 * (s0 + s) + 1];
  }
  float* op = outp + (size_t)row * outStride + 2 * s0;
  if (NSW == 2) {
    *(float4*)op = make_float4(acc[0], acc[1], acc[2], acc[3]);
  } else {
    *(float2*)op = make_float2(acc[0], acc[1]);
  }
}

extern "C" void kernel_launch(void* const* d_in, const int* in_sizes, int n_in,
                              void* d_out, int out_size, void* d_ws, size_t ws_size,
                              hipStream_t stream) {
  const float* x = (const float*)d_in[0];
  float* out = (float*)d_out;
  float* wsf = (float*)d_ws;

  // ws layout (float offsets)
  float* out2 = wsf + 0;                   // [8192][8]
  float* out3 = wsf + 65536;               // [8192][16]
  float* out4 = wsf + 196608;              // [8192][32]
  float4* prm = (float4*)(wsf + 458752);   // 17492 float4
  float* cstf = wsf + 528720;              // 126 floats

  MaskArgs ma;
  for (int d = 0; d < 6; ++d) {
    ma.fm[d] = (const float*)d_in[1 + 3 * d];
    ma.cp[d] = (const float*)d_in[2 + 3 * d];
    ma.lr[d] = (const float*)d_in[3 + 3 * d];
  }
  ma.out_masks = out;
  ma.prm = prm;
  ma.cstf = cstf;
  hipLaunchKernelGGL(ndt_masks, dim3(63), dim3(64), 0, stream, ma);

  // levels 0-2 fused
  hipLaunchKernelGGL(ndt_l012, dim3(B_SZ / 32), dim3(256), 0, stream,
                     x, prm, cstf, out2);
  // level 3: 8 stumps; 32 rowblks x 8 groups, XCD-swizzled
  hipLaunchKernelGGL((ndt_big<8, 1, 8>), dim3(32 * 8), dim3(256), 0, stream,
                     x, out2, prm + 1812, cstf + 14, out3, 16);
  // level 4: 16 stumps; 32 rowblks x 16 groups
  hipLaunchKernelGGL((ndt_big<16, 1, 16>), dim3(32 * 16), dim3(256), 0, stream,
                     x, out3, prm + 3924, cstf + 30, out4, 32);
  // level 5: 32 stumps; 32 rowblks x 16 groups (NSW=2)
  hipLaunchKernelGGL((ndt_big<32, 2, 16>), dim3(32 * 16), dim3(256), 0, stream,
                     x, out4, prm + 8276, cstf + 62, out, 64);
}

// Round 8
// 91.634 us; speedup vs baseline: 1.0961x; 1.0961x over previous
//
#include <hip/hip_runtime.h>

#define B_SZ 8192

// ---------------- masks (exact 1.5-entmax via bisection) + fused params ----------------
struct MaskArgs {
  const float* fm[6];
  const float* cp[6];
  const float* lr[6];
  float* out_masks;  // d_out base
  float4* prm;       // fused params {c10, ml0/8, ml1/8, 0}
  float* cstf;       // flat per-output 0.5*sum(ml): level d at 2*cstOff[d]
};

__device__ __forceinline__ float wave_max(float v) {
#pragma unroll
  for (int o = 32; o > 0; o >>= 1) v = fmaxf(v, __shfl_xor(v, o));
  return v;
}
__device__ __forceinline__ float wave_sum(float v) {
#pragma unroll
  for (int o = 32; o > 0; o >>= 1) v += __shfl_xor(v, o);
  return v;
}

__global__ __launch_bounds__(64) void ndt_masks(MaskArgs a) {
  const int maskOff[6] = {524288, 524544, 525060, 526100, 528212, 532564};
  const int prmOff[6]  = {0, 256, 772, 1812, 3924, 8276};
  const int cstOff[6]  = {0, 1, 3, 7, 15, 31};
  int bid = blockIdx.x, lane = threadIdx.x;
  int d = 0, s = bid, n = 1;
  while (s >= n) { s -= n; n <<= 1; ++d; }   // level d, stump s, n = 2^d
  int Fd = 256 + ((d > 0) ? n : 0);

  const float* fm = a.fm[d] + (size_t)s * Fd;
  float y[5];
#pragma unroll
  for (int j = 0; j < 5; ++j) {
    int f = lane + 64 * j;
    y[j] = (f < Fd) ? fm[f] * 0.5f : -3.0e38f;
  }
  float m = fmaxf(fmaxf(fmaxf(y[0], y[1]), fmaxf(y[2], y[3])), y[4]);
  m = wave_max(m);
#pragma unroll
  for (int j = 0; j < 5; ++j) y[j] -= m;

  // solve sum clip(y - tau, 0)^2 = 1 ; tau in [-1, 0], strictly decreasing in tau
  float lo = -1.f, hi = 0.f;
  for (int it = 0; it < 24; ++it) {
    float tau = 0.5f * (lo + hi);
    float ss = 0.f;
#pragma unroll
    for (int j = 0; j < 5; ++j) {
      float v = fmaxf(y[j] - tau, 0.f);
      ss = __builtin_fmaf(v, v, ss);
    }
    ss = wave_sum(ss);
    if (ss >= 1.f) lo = tau; else hi = tau;
  }
  float tau = 0.5f * (lo + hi);

  float* mo = a.out_masks + maskOff[d] + (size_t)s * Fd;
  const float* cp = a.cp[d] + (size_t)s * Fd * 2;
  const float* lr = a.lr[d] + (size_t)s * Fd * 2;
  float4* pr = a.prm + prmOff[d] + (size_t)s * Fd;
  float sum0 = 0.f, sum1 = 0.f;
#pragma unroll
  for (int j = 0; j < 5; ++j) {
    int f = lane + 64 * j;
    if (f < Fd) {
      float v = fmaxf(y[j] - tau, 0.f);
      float mk = v * v;
      mo[f] = mk;
      float c0 = cp[2 * f], c1 = cp[2 * f + 1];
      float ml0 = lr[2 * f] * mk, ml1 = lr[2 * f + 1] * mk;
      sum0 += ml0;
      sum1 += ml1;
      // store ml/8: entpair returns e' = 8e, so e'*(ml/8) = e*ml
      pr[f] = make_float4(c1 - c0, ml0 * 0.125f, ml1 * 0.125f, 0.f);
    }
  }
  sum0 = wave_sum(sum0);
  sum1 = wave_sum(sum1);
  if (lane == 0) {
    a.cstf[2 * (cstOff[d] + s)] = 0.5f * sum0;
    a.cstf[2 * (cstOff[d] + s) + 1] = 0.5f * sum1;
  }
}

// 2-elem entmax15 closed form (scaled): t = c10 - x; tc = clamp(t,-2,2);
// e' = tc*sqrt(8 - tc^2) = 8*e;  p0 = 0.5 + e'/8, p1 = 0.5 - e'/8.
// The 1/8 is folded into the ml params at build time.
__device__ __forceinline__ float entpair(float c10, float xv) {
  float t = c10 - xv;
  float tc = __builtin_amdgcn_fmed3f(t, -2.f, 2.f);
  float u = __builtin_fmaf(tc, -tc, 8.0f);
  return tc * __builtin_amdgcn_sqrtf(u);
}

// ---------------- levels 0-2 fused: 32-row blocks, 8 groups x 32 lanes ----------------
__global__ __launch_bounds__(256) void ndt_l012(const float* __restrict__ x,
                                                const float4* __restrict__ prm,
                                                const float* __restrict__ cstf,
                                                float* __restrict__ out2) {
  __shared__ float xls[256 * 32];
  __shared__ float4 pl[1812];
  __shared__ float pbuf[8][2][32];
  int tid = threadIdx.x;
  int r = tid & 31, c = tid >> 5;
  int b0 = blockIdx.x * 32;
  for (int i = tid; i < 1812; i += 256) pl[i] = prm[i];
  {
    const float4* xp = (const float4*)(x + (size_t)(b0 + r) * 256 + c * 32);
#pragma unroll
    for (int j = 0; j < 8; ++j) {
      float4 g = xp[j];
      int f = c * 32 + 4 * j;
      xls[(f + 0) * 32 + (r ^ ((4 * j + 0) & 31))] = g.x;
      xls[(f + 1) * 32 + (r ^ ((4 * j + 1) & 31))] = g.y;
      xls[(f + 2) * 32 + (r ^ ((4 * j + 2) & 31))] = g.z;
      xls[(f + 3) * 32 + (r ^ ((4 * j + 3) & 31))] = g.w;
    }
  }
  __syncthreads();
  // ---- L0: group c -> features [c*32, c*32+32)
  float a0 = 0.f, a1 = 0.f;
#pragma unroll
  for (int j = 0; j < 32; ++j) {
    int f = c * 32 + j;
    float xv = xls[f * 32 + (r ^ j)];
    float4 p = pl[f];
    float e = entpair(p.x, xv);
    a0 = __builtin_fmaf(e, p.y, a0);
    a1 = __builtin_fmaf(-e, p.z, a1);
  }
  pbuf[c][0][r] = a0;
  pbuf[c][1][r] = a1;
  __syncthreads();
  float xe1[2];
#pragma unroll
  for (int o = 0; o < 2; ++o) {
    float v = cstf[o];
#pragma unroll
    for (int k = 0; k < 8; ++k) v += pbuf[k][o][r];
    xe1[o] = v;
  }
  __syncthreads();
  // ---- L1: stump c>>2, feature slice (c&3)*64; extras on slice 0
  {
    int s = c >> 2, fs = c & 3;
    const float4* ps = &pl[256 + s * 258];
    a0 = 0.f;
    a1 = 0.f;
#pragma unroll
    for (int j = 0; j < 64; ++j) {
      int f = fs * 64 + j;
      float xv = xls[f * 32 + (r ^ (f & 31))];
      float4 p = ps[f];
      float e = entpair(p.x, xv);
      a0 = __builtin_fmaf(e, p.y, a0);
      a1 = __builtin_fmaf(-e, p.z, a1);
    }
    if (fs == 0) {
#pragma unroll
      for (int o = 0; o < 2; ++o) {
        float4 p = ps[256 + o];
        float e = entpair(p.x, xe1[o]);
        a0 = __builtin_fmaf(e, p.y, a0);
        a1 = __builtin_fmaf(-e, p.z, a1);
      }
    }
    pbuf[c][0][r] = a0;
    pbuf[c][1][r] = a1;
  }
  __syncthreads();
  float xe2[4];
#pragma unroll
  for (int s = 0; s < 2; ++s)
#pragma unroll
    for (int o = 0; o < 2; ++o) {
      float v = cstf[2 + 2 * s + o];
#pragma unroll
      for (int k = 0; k < 4; ++k) v += pbuf[4 * s + k][o][r];
      xe2[2 * s + o] = v;
    }
  __syncthreads();
  // ---- L2: stump c>>1, feature slice (c&1)*128; extras on slice 0
  {
    int s = c >> 1, fs = c & 1;
    const float4* ps = &pl[772 + s * 260];
    a0 = 0.f;
    a1 = 0.f;
#pragma unroll
    for (int j = 0; j < 128; ++j) {
      int f = fs * 128 + j;
      float xv = xls[f * 32 + (r ^ (f & 31))];
      float4 p = ps[f];
      float e = entpair(p.x, xv);
      a0 = __builtin_fmaf(e, p.y, a0);
      a1 = __builtin_fmaf(-e, p.z, a1);
    }
    if (fs == 0) {
#pragma unroll
      for (int o = 0; o < 4; ++o) {
        float4 p = ps[256 + o];
        float e = entpair(p.x, xe2[o]);
        a0 = __builtin_fmaf(e, p.y, a0);
        a1 = __builtin_fmaf(-e, p.z, a1);
      }
    }
    pbuf[c][0][r] = a0;
    pbuf[c][1][r] = a1;
  }
  __syncthreads();
  // ---- reduce L2 -> out2[row][8]; groups 0/1 write float4 halves
  if (c < 2) {
    float o4[4];
#pragma unroll
    for (int i = 0; i < 4; ++i) {
      int s = 2 * c + (i >> 1), o = i & 1;
      float v = cstf[6 + 2 * s + o];
#pragma unroll
      for (int k = 0; k < 2; ++k) v += pbuf[2 * s + k][o][r];
      o4[i] = v;
    }
    *(float4*)(out2 + (size_t)(b0 + r) * 8 + 4 * c) =
        make_float4(o4[0], o4[1], o4[2], o4[3]);
  }
}

// ---------------- big levels (3,4,5): one stump per block, feature-split ----------
// Block = 256*FSPLIT threads: FSPLIT groups of 256 rows; group fh handles base
// features [fh*BP, (fh+1)*BP) (BP=256/FSPLIT); the last group also handles the EX
// prev-level features (loaded AFTER the main loop to keep VGPR<=64 -> 8 waves/SIMD).
// Partials combine via a small LDS buffer (2-way bank aliasing = free).
// Params in LDS, wave-uniform broadcast b128; x streamed from global (L2-resident).
template <int EX, int FSPLIT>
__global__ __launch_bounds__(256 * FSPLIT, 4) void ndt_big2(
    const float* __restrict__ x, const float* __restrict__ prev,
    const float4* __restrict__ prmL, const float* __restrict__ cstL,
    float* __restrict__ outp, int outStride) {
  constexpr int FD = 256 + EX;
  constexpr int BP = 256 / FSPLIT;
  __shared__ float4 pl[FD];
  __shared__ float2 pb2[(FSPLIT > 1 ? FSPLIT - 1 : 1) * 256];
  int tid = threadIdx.x;
  int row = tid & 255;
  int fh = tid >> 8;
  int s = blockIdx.y;
  for (int i = tid; i < FD; i += 256 * FSPLIT) pl[i] = prmL[(size_t)s * FD + i];
  __syncthreads();

  int grow = blockIdx.x * 256 + row;
  float a0 = 0.f, a1 = 0.f;

  const float4* xp = (const float4*)(x + (size_t)grow * 256 + fh * BP);
#pragma unroll 2
  for (int gg = 0; gg < BP / 16; ++gg) {
    float4 xq[4];
#pragma unroll
    for (int q = 0; q < 4; ++q) xq[q] = xp[4 * gg + q];
#pragma unroll
    for (int q = 0; q < 4; ++q) {
      float xa[4] = {xq[q].x, xq[q].y, xq[q].z, xq[q].w};
#pragma unroll
      for (int i = 0; i < 4; ++i) {
        float4 p = pl[fh * BP + 16 * gg + 4 * q + i];  // wave-uniform -> broadcast
        float e = entpair(p.x, xa[i]);
        a0 = __builtin_fmaf(e, p.y, a0);
        a1 = __builtin_fmaf(-e, p.z, a1);
      }
    }
  }
  // tail: extra features = prev-level outputs (loaded late: short live range)
  if (fh == FSPLIT - 1) {
    const float4* pvp = (const float4*)(prev + (size_t)grow * EX);
#pragma unroll
    for (int k = 0; k < EX / 4; ++k) {
      float4 v = pvp[k];
      float va[4] = {v.x, v.y, v.z, v.w};
#pragma unroll
      for (int o = 0; o < 4; ++o) {
        float4 p = pl[256 + 4 * k + o];
        float e = entpair(p.x, va[o]);
        a0 = __builtin_fmaf(e, p.y, a0);
        a1 = __builtin_fmaf(-e, p.z, a1);
      }
    }
  }
  if (FSPLIT > 1) {
    if (fh > 0) pb2[(fh - 1) * 256 + row] = make_float2(a0, a1);
    __syncthreads();
    if (fh == 0) {
#pragma unroll
      for (int k = 0; k < FSPLIT - 1; ++k) {
        float2 t = pb2[k * 256 + row];
        a0 += t.x;
        a1 += t.y;
      }
    }
  }
  if (fh == 0) {
    a0 += cstL[2 * s];
    a1 += cstL[2 * s + 1];
    *(float2*)(outp + (size_t)grow * outStride + 2 * s) = make_float2(a0, a1);
  }
}

extern "C" void kernel_launch(void* const* d_in, const int* in_sizes, int n_in,
                              void* d_out, int out_size, void* d_ws, size_t ws_size,
                              hipStream_t stream) {
  const float* x = (const float*)d_in[0];
  float* out = (float*)d_out;
  float* wsf = (float*)d_ws;

  // ws layout (float offsets)
  float* out2 = wsf + 0;                   // [8192][8]
  float* out3 = wsf + 65536;               // [8192][16]
  float* out4 = wsf + 196608;              // [8192][32]
  float4* prm = (float4*)(wsf + 458752);   // 17492 float4
  float* cstf = wsf + 528720;              // 126 floats

  MaskArgs ma;
  for (int d = 0; d < 6; ++d) {
    ma.fm[d] = (const float*)d_in[1 + 3 * d];
    ma.cp[d] = (const float*)d_in[2 + 3 * d];
    ma.lr[d] = (const float*)d_in[3 + 3 * d];
  }
  ma.out_masks = out;
  ma.prm = prm;
  ma.cstf = cstf;
  hipLaunchKernelGGL(ndt_masks, dim3(63), dim3(64), 0, stream, ma);

  // levels 0-2 fused
  hipLaunchKernelGGL(ndt_l012, dim3(B_SZ / 32), dim3(256), 0, stream,
                     x, prm, cstf, out2);
  // level 3: 8 stumps; 1024-thr blocks (4-way feature split), grid (32, 8)
  hipLaunchKernelGGL((ndt_big2<8, 4>), dim3(B_SZ / 256, 8), dim3(1024), 0, stream,
                     x, out2, prm + 1812, cstf + 14, out3, 16);
  // level 4: 16 stumps; 1024-thr blocks (4-way split), grid (32, 16)
  hipLaunchKernelGGL((ndt_big2<16, 4>), dim3(B_SZ / 256, 16), dim3(1024), 0, stream,
                     x, out3, prm + 3924, cstf + 30, out4, 32);
  // level 5: 32 stumps; 512-thr blocks (2-way split), grid (32, 32)
  hipLaunchKernelGGL((ndt_big2<32, 2>), dim3(B_SZ / 256, 32), dim3(512), 0, stream,
                     x, out4, prm + 8276, cstf + 62, out, 64);
}

// Round 9
// 91.239 us; speedup vs baseline: 1.1008x; 1.0043x over previous
//
#include <hip/hip_runtime.h>

#define B_SZ 8192

// ---------------- transpose x [8192,256] -> xT [256][8192] ----------------
__global__ __launch_bounds__(256) void ndt_transpose(const float* __restrict__ x,
                                                     float* __restrict__ xT) {
  __shared__ float tile[32][33];
  int f0 = blockIdx.x * 32;
  int b0 = blockIdx.y * 32;
  int tx = threadIdx.x, ty = threadIdx.y;
#pragma unroll
  for (int k = 0; k < 32; k += 8)
    tile[ty + k][tx] = x[(size_t)(b0 + ty + k) * 256 + f0 + tx];
  __syncthreads();
#pragma unroll
  for (int k = 0; k < 32; k += 8)
    xT[(size_t)(f0 + ty + k) * B_SZ + b0 + tx] = tile[tx][ty + k];
}

// ---------------- masks (exact 1.5-entmax via bisection) + fused params ----------------
struct MaskArgs {
  const float* fm[6];
  const float* cp[6];
  const float* lr[6];
  float* out_masks;  // d_out base
  float4* prm;       // fused params {c10, ml0/8, ml1/8, 0}
  float* cstf;       // flat per-output 0.5*sum(ml): level d at 2*cstOff[d]
};

__device__ __forceinline__ float wave_max(float v) {
#pragma unroll
  for (int o = 32; o > 0; o >>= 1) v = fmaxf(v, __shfl_xor(v, o));
  return v;
}
__device__ __forceinline__ float wave_sum(float v) {
#pragma unroll
  for (int o = 32; o > 0; o >>= 1) v += __shfl_xor(v, o);
  return v;
}

__global__ __launch_bounds__(64) void ndt_masks(MaskArgs a) {
  const int maskOff[6] = {524288, 524544, 525060, 526100, 528212, 532564};
  const int prmOff[6]  = {0, 256, 772, 1812, 3924, 8276};
  const int cstOff[6]  = {0, 1, 3, 7, 15, 31};
  int bid = blockIdx.x, lane = threadIdx.x;
  int d = 0, s = bid, n = 1;
  while (s >= n) { s -= n; n <<= 1; ++d; }   // level d, stump s, n = 2^d
  int Fd = 256 + ((d > 0) ? n : 0);

  const float* fm = a.fm[d] + (size_t)s * Fd;
  float y[5];
#pragma unroll
  for (int j = 0; j < 5; ++j) {
    int f = lane + 64 * j;
    y[j] = (f < Fd) ? fm[f] * 0.5f : -3.0e38f;
  }
  float m = fmaxf(fmaxf(fmaxf(y[0], y[1]), fmaxf(y[2], y[3])), y[4]);
  m = wave_max(m);
#pragma unroll
  for (int j = 0; j < 5; ++j) y[j] -= m;

  // solve sum clip(y - tau, 0)^2 = 1 ; tau in [-1, 0], strictly decreasing in tau
  float lo = -1.f, hi = 0.f;
  for (int it = 0; it < 24; ++it) {
    float tau = 0.5f * (lo + hi);
    float ss = 0.f;
#pragma unroll
    for (int j = 0; j < 5; ++j) {
      float v = fmaxf(y[j] - tau, 0.f);
      ss = __builtin_fmaf(v, v, ss);
    }
    ss = wave_sum(ss);
    if (ss >= 1.f) lo = tau; else hi = tau;
  }
  float tau = 0.5f * (lo + hi);

  float* mo = a.out_masks + maskOff[d] + (size_t)s * Fd;
  const float* cp = a.cp[d] + (size_t)s * Fd * 2;
  const float* lr = a.lr[d] + (size_t)s * Fd * 2;
  float4* pr = a.prm + prmOff[d] + (size_t)s * Fd;
  float sum0 = 0.f, sum1 = 0.f;
#pragma unroll
  for (int j = 0; j < 5; ++j) {
    int f = lane + 64 * j;
    if (f < Fd) {
      float v = fmaxf(y[j] - tau, 0.f);
      float mk = v * v;
      mo[f] = mk;
      float c0 = cp[2 * f], c1 = cp[2 * f + 1];
      float ml0 = lr[2 * f] * mk, ml1 = lr[2 * f + 1] * mk;
      sum0 += ml0;
      sum1 += ml1;
      // store ml/8: entpair returns e' = 8e, so e'*(ml/8) = e*ml
      pr[f] = make_float4(c1 - c0, ml0 * 0.125f, ml1 * 0.125f, 0.f);
    }
  }
  sum0 = wave_sum(sum0);
  sum1 = wave_sum(sum1);
  if (lane == 0) {
    a.cstf[2 * (cstOff[d] + s)] = 0.5f * sum0;
    a.cstf[2 * (cstOff[d] + s) + 1] = 0.5f * sum1;
  }
}

// 2-elem entmax15 closed form (scaled): t = c10 - x; tc = clamp(t,-2,2);
// e' = tc*sqrt(8 - tc^2) = 8*e;  p0 = 0.5 + e'/8, p1 = 0.5 - e'/8.
// The 1/8 is folded into the ml params at build time.
__device__ __forceinline__ float entpair(float c10, float xv) {
  float t = c10 - xv;
  float tc = __builtin_amdgcn_fmed3f(t, -2.f, 2.f);
  float u = __builtin_fmaf(tc, -tc, 8.0f);
  return tc * __builtin_amdgcn_sqrtf(u);
}

// ---------------- levels 0-2 fused: 32-row blocks, 8 groups x 32 lanes ----------------
// Writes out2 TRANSPOSED: out2T[o][row], o in [0,8).
__global__ __launch_bounds__(256) void ndt_l012(const float* __restrict__ x,
                                                const float4* __restrict__ prm,
                                                const float* __restrict__ cstf,
                                                float* __restrict__ out2T) {
  __shared__ float xls[256 * 32];
  __shared__ float4 pl[1812];
  __shared__ float pbuf[8][2][32];
  int tid = threadIdx.x;
  int r = tid & 31, c = tid >> 5;
  int b0 = blockIdx.x * 32;
  for (int i = tid; i < 1812; i += 256) pl[i] = prm[i];
  {
    const float4* xp = (const float4*)(x + (size_t)(b0 + r) * 256 + c * 32);
#pragma unroll
    for (int j = 0; j < 8; ++j) {
      float4 g = xp[j];
      int f = c * 32 + 4 * j;
      xls[(f + 0) * 32 + (r ^ ((4 * j + 0) & 31))] = g.x;
      xls[(f + 1) * 32 + (r ^ ((4 * j + 1) & 31))] = g.y;
      xls[(f + 2) * 32 + (r ^ ((4 * j + 2) & 31))] = g.z;
      xls[(f + 3) * 32 + (r ^ ((4 * j + 3) & 31))] = g.w;
    }
  }
  __syncthreads();
  // ---- L0: group c -> features [c*32, c*32+32)
  float a0 = 0.f, a1 = 0.f;
#pragma unroll
  for (int j = 0; j < 32; ++j) {
    int f = c * 32 + j;
    float xv = xls[f * 32 + (r ^ j)];
    float4 p = pl[f];
    float e = entpair(p.x, xv);
    a0 = __builtin_fmaf(e, p.y, a0);
    a1 = __builtin_fmaf(-e, p.z, a1);
  }
  pbuf[c][0][r] = a0;
  pbuf[c][1][r] = a1;
  __syncthreads();
  float xe1[2];
#pragma unroll
  for (int o = 0; o < 2; ++o) {
    float v = cstf[o];
#pragma unroll
    for (int k = 0; k < 8; ++k) v += pbuf[k][o][r];
    xe1[o] = v;
  }
  __syncthreads();
  // ---- L1: stump c>>2, feature slice (c&3)*64; extras on slice 0
  {
    int s = c >> 2, fs = c & 3;
    const float4* ps = &pl[256 + s * 258];
    a0 = 0.f;
    a1 = 0.f;
#pragma unroll
    for (int j = 0; j < 64; ++j) {
      int f = fs * 64 + j;
      float xv = xls[f * 32 + (r ^ (f & 31))];
      float4 p = ps[f];
      float e = entpair(p.x, xv);
      a0 = __builtin_fmaf(e, p.y, a0);
      a1 = __builtin_fmaf(-e, p.z, a1);
    }
    if (fs == 0) {
#pragma unroll
      for (int o = 0; o < 2; ++o) {
        float4 p = ps[256 + o];
        float e = entpair(p.x, xe1[o]);
        a0 = __builtin_fmaf(e, p.y, a0);
        a1 = __builtin_fmaf(-e, p.z, a1);
      }
    }
    pbuf[c][0][r] = a0;
    pbuf[c][1][r] = a1;
  }
  __syncthreads();
  float xe2[4];
#pragma unroll
  for (int s = 0; s < 2; ++s)
#pragma unroll
    for (int o = 0; o < 2; ++o) {
      float v = cstf[2 + 2 * s + o];
#pragma unroll
      for (int k = 0; k < 4; ++k) v += pbuf[4 * s + k][o][r];
      xe2[2 * s + o] = v;
    }
  __syncthreads();
  // ---- L2: stump c>>1, feature slice (c&1)*128; extras on slice 0
  {
    int s = c >> 1, fs = c & 1;
    const float4* ps = &pl[772 + s * 260];
    a0 = 0.f;
    a1 = 0.f;
#pragma unroll
    for (int j = 0; j < 128; ++j) {
      int f = fs * 128 + j;
      float xv = xls[f * 32 + (r ^ (f & 31))];
      float4 p = ps[f];
      float e = entpair(p.x, xv);
      a0 = __builtin_fmaf(e, p.y, a0);
      a1 = __builtin_fmaf(-e, p.z, a1);
    }
    if (fs == 0) {
#pragma unroll
      for (int o = 0; o < 4; ++o) {
        float4 p = ps[256 + o];
        float e = entpair(p.x, xe2[o]);
        a0 = __builtin_fmaf(e, p.y, a0);
        a1 = __builtin_fmaf(-e, p.z, a1);
      }
    }
    pbuf[c][0][r] = a0;
    pbuf[c][1][r] = a1;
  }
  __syncthreads();
  // ---- reduce L2 -> out2T[4c+i][b0+r] (coalesced 128-B stores per group)
  if (c < 2) {
#pragma unroll
    for (int i = 0; i < 4; ++i) {
      int s = 2 * c + (i >> 1), o = i & 1;
      float v = cstf[6 + 2 * s + o];
#pragma unroll
      for (int k = 0; k < 2; ++k) v += pbuf[2 * s + k][o][r];
      out2T[(size_t)(4 * c + i) * B_SZ + b0 + r] = v;
    }
  }
}

// ---------------- big levels (3,4,5): feature-major, lane <-> column ----------
// xT[f][8192], prevT[o][8192]: every wave-load = 64 consecutive floats (4 lines,
// fully shared) instead of 64 scattered lines. Params in LDS (uniform broadcast).
// Block 256 thr = 256 columns; NSW stumps per block; grid (32 colblks, n/NSW).
// 32%8==0 -> column-slice bx lands on XCD bx%8 for every stump-group: xT slice
// (1 MB/XCD) stays L2-resident across all re-reads.
template <int EX, int NSW, bool FINAL>
__global__ __launch_bounds__(256, 4) void ndt_bigT(const float* __restrict__ xT,
                                                   const float* __restrict__ prevT,
                                                   const float4* __restrict__ prmL,
                                                   const float* __restrict__ cstL,
                                                   float* __restrict__ outp) {
  constexpr int FD = 256 + EX;
  __shared__ float4 pl[NSW * FD];
  int tid = threadIdx.x;
  int s0 = blockIdx.y * NSW;
  for (int i = tid; i < NSW * FD; i += 256) pl[i] = prmL[(size_t)s0 * FD + i];
  __syncthreads();

  int col = blockIdx.x * 256 + tid;
  float acc[2 * NSW];
#pragma unroll
  for (int i = 0; i < 2 * NSW; ++i) acc[i] = 0.f;

  const float* xc = xT + col;
#pragma unroll 8
  for (int f = 0; f < 256; ++f) {
    float xv = xc[(size_t)f * B_SZ];
#pragma unroll
    for (int s = 0; s < NSW; ++s) {
      float4 p = pl[s * FD + f];  // wave-uniform -> LDS broadcast
      float e = entpair(p.x, xv);
      acc[2 * s] = __builtin_fmaf(e, p.y, acc[2 * s]);
      acc[2 * s + 1] = __builtin_fmaf(-e, p.z, acc[2 * s + 1]);
    }
  }
  const float* pc = prevT + col;
#pragma unroll
  for (int o = 0; o < EX; ++o) {
    float pv = pc[(size_t)o * B_SZ];
#pragma unroll
    for (int s = 0; s < NSW; ++s) {
      float4 p = pl[s * FD + 256 + o];
      float e = entpair(p.x, pv);
      acc[2 * s] = __builtin_fmaf(e, p.y, acc[2 * s]);
      acc[2 * s + 1] = __builtin_fmaf(-e, p.z, acc[2 * s + 1]);
    }
  }
#pragma unroll
  for (int s = 0; s < NSW; ++s) {
    float r0 = acc[2 * s] + cstL[2 * (s0 + s)];
    float r1 = acc[2 * s + 1] + cstL[2 * (s0 + s) + 1];
    if (FINAL) {
      *(float2*)(outp + (size_t)col * 64 + 2 * (s0 + s)) = make_float2(r0, r1);
    } else {
      outp[(size_t)(2 * (s0 + s)) * B_SZ + col] = r0;
      outp[(size_t)(2 * (s0 + s) + 1) * B_SZ + col] = r1;
    }
  }
}

extern "C" void kernel_launch(void* const* d_in, const int* in_sizes, int n_in,
                              void* d_out, int out_size, void* d_ws, size_t ws_size,
                              hipStream_t stream) {
  const float* x = (const float*)d_in[0];
  float* out = (float*)d_out;
  float* wsf = (float*)d_ws;

  // ws layout (float offsets)
  float* xT = wsf + 0;                     // [256][8192]
  float* out2T = wsf + 2097152;            // [8][8192]
  float* out3T = wsf + 2162688;            // [16][8192]
  float* out4T = wsf + 2293760;            // [32][8192]
  float4* prm = (float4*)(wsf + 2555904);  // 17492 float4
  float* cstf = wsf + 2625872;             // 126 floats

  hipLaunchKernelGGL(ndt_transpose, dim3(8, B_SZ / 32), dim3(32, 8), 0, stream,
                     x, xT);

  MaskArgs ma;
  for (int d = 0; d < 6; ++d) {
    ma.fm[d] = (const float*)d_in[1 + 3 * d];
    ma.cp[d] = (const float*)d_in[2 + 3 * d];
    ma.lr[d] = (const float*)d_in[3 + 3 * d];
  }
  ma.out_masks = out;
  ma.prm = prm;
  ma.cstf = cstf;
  hipLaunchKernelGGL(ndt_masks, dim3(63), dim3(64), 0, stream, ma);

  // levels 0-2 fused (row-major x; writes out2T transposed)
  hipLaunchKernelGGL(ndt_l012, dim3(B_SZ / 32), dim3(256), 0, stream,
                     x, prm, cstf, out2T);
  // level 3: 8 stumps; grid (32, 8)
  hipLaunchKernelGGL((ndt_bigT<8, 1, false>), dim3(32, 8), dim3(256), 0, stream,
                     xT, out2T, prm + 1812, cstf + 14, out3T);
  // level 4: 16 stumps; grid (32, 16)
  hipLaunchKernelGGL((ndt_bigT<16, 1, false>), dim3(32, 16), dim3(256), 0, stream,
                     xT, out3T, prm + 3924, cstf + 30, out4T);
  // level 5: 32 stumps; grid (32, 16), NSW=2, final row-major write
  hipLaunchKernelGGL((ndt_bigT<32, 2, true>), dim3(32, 16), dim3(256), 0, stream,
                     xT, out4T, prm + 8276, cstf + 62, out);
}

// Round 10
// 79.454 us; speedup vs baseline: 1.2641x; 1.1483x over previous
//
#include <hip/hip_runtime.h>

#define B_SZ 8192
#define SP 8256  // padded row stride (floats): breaks 32KB power-of-2 L2-channel aliasing

// ---------------- transpose x [8192,256] -> xT [256][SP] ----------------
__global__ __launch_bounds__(256) void ndt_transpose(const float* __restrict__ x,
                                                     float* __restrict__ xT) {
  __shared__ float tile[32][33];
  int f0 = blockIdx.x * 32;
  int b0 = blockIdx.y * 32;
  int tx = threadIdx.x, ty = threadIdx.y;
#pragma unroll
  for (int k = 0; k < 32; k += 8)
    tile[ty + k][tx] = x[(size_t)(b0 + ty + k) * 256 + f0 + tx];
  __syncthreads();
#pragma unroll
  for (int k = 0; k < 32; k += 8)
    xT[(size_t)(f0 + ty + k) * SP + b0 + tx] = tile[tx][ty + k];
}

// ---------------- masks (exact 1.5-entmax via bisection) + fused params ----------------
struct MaskArgs {
  const float* fm[6];
  const float* cp[6];
  const float* lr[6];
  float* out_masks;  // d_out base
  float4* prm;       // fused params {c10, ml0/8, ml1/8, 0}
  float* cstf;       // flat per-output 0.5*sum(ml): level d at 2*cstOff[d]
};

__device__ __forceinline__ float wave_max(float v) {
#pragma unroll
  for (int o = 32; o > 0; o >>= 1) v = fmaxf(v, __shfl_xor(v, o));
  return v;
}
__device__ __forceinline__ float wave_sum(float v) {
#pragma unroll
  for (int o = 32; o > 0; o >>= 1) v += __shfl_xor(v, o);
  return v;
}

__global__ __launch_bounds__(64) void ndt_masks(MaskArgs a) {
  const int maskOff[6] = {524288, 524544, 525060, 526100, 528212, 532564};
  const int prmOff[6]  = {0, 256, 772, 1812, 3924, 8276};
  const int cstOff[6]  = {0, 1, 3, 7, 15, 31};
  int bid = blockIdx.x, lane = threadIdx.x;
  int d = 0, s = bid, n = 1;
  while (s >= n) { s -= n; n <<= 1; ++d; }   // level d, stump s, n = 2^d
  int Fd = 256 + ((d > 0) ? n : 0);

  const float* fm = a.fm[d] + (size_t)s * Fd;
  float y[5];
#pragma unroll
  for (int j = 0; j < 5; ++j) {
    int f = lane + 64 * j;
    y[j] = (f < Fd) ? fm[f] * 0.5f : -3.0e38f;
  }
  float m = fmaxf(fmaxf(fmaxf(y[0], y[1]), fmaxf(y[2], y[3])), y[4]);
  m = wave_max(m);
#pragma unroll
  for (int j = 0; j < 5; ++j) y[j] -= m;

  // solve sum clip(y - tau, 0)^2 = 1 ; tau in [-1, 0], strictly decreasing in tau
  float lo = -1.f, hi = 0.f;
  for (int it = 0; it < 24; ++it) {
    float tau = 0.5f * (lo + hi);
    float ss = 0.f;
#pragma unroll
    for (int j = 0; j < 5; ++j) {
      float v = fmaxf(y[j] - tau, 0.f);
      ss = __builtin_fmaf(v, v, ss);
    }
    ss = wave_sum(ss);
    if (ss >= 1.f) lo = tau; else hi = tau;
  }
  float tau = 0.5f * (lo + hi);

  float* mo = a.out_masks + maskOff[d] + (size_t)s * Fd;
  const float* cp = a.cp[d] + (size_t)s * Fd * 2;
  const float* lr = a.lr[d] + (size_t)s * Fd * 2;
  float4* pr = a.prm + prmOff[d] + (size_t)s * Fd;
  float sum0 = 0.f, sum1 = 0.f;
#pragma unroll
  for (int j = 0; j < 5; ++j) {
    int f = lane + 64 * j;
    if (f < Fd) {
      float v = fmaxf(y[j] - tau, 0.f);
      float mk = v * v;
      mo[f] = mk;
      float c0 = cp[2 * f], c1 = cp[2 * f + 1];
      float ml0 = lr[2 * f] * mk, ml1 = lr[2 * f + 1] * mk;
      sum0 += ml0;
      sum1 += ml1;
      // store ml/8: entpair returns e' = 8e, so e'*(ml/8) = e*ml
      pr[f] = make_float4(c1 - c0, ml0 * 0.125f, ml1 * 0.125f, 0.f);
    }
  }
  sum0 = wave_sum(sum0);
  sum1 = wave_sum(sum1);
  if (lane == 0) {
    a.cstf[2 * (cstOff[d] + s)] = 0.5f * sum0;
    a.cstf[2 * (cstOff[d] + s) + 1] = 0.5f * sum1;
  }
}

// 2-elem entmax15 closed form (scaled): t = c10 - x; tc = clamp(t,-2,2);
// e' = tc*sqrt(8 - tc^2) = 8*e;  p0 = 0.5 + e'/8, p1 = 0.5 - e'/8.
// The 1/8 is folded into the ml params at build time.
__device__ __forceinline__ float entpair(float c10, float xv) {
  float t = c10 - xv;
  float tc = __builtin_amdgcn_fmed3f(t, -2.f, 2.f);
  float u = __builtin_fmaf(tc, -tc, 8.0f);
  return tc * __builtin_amdgcn_sqrtf(u);
}

// ---------------- levels 0-2 fused: 32-row blocks, 8 groups x 32 lanes ----------------
// Writes out2 TRANSPOSED with padded stride: out2T[o][row], o in [0,8).
__global__ __launch_bounds__(256) void ndt_l012(const float* __restrict__ x,
                                                const float4* __restrict__ prm,
                                                const float* __restrict__ cstf,
                                                float* __restrict__ out2T) {
  __shared__ float xls[256 * 32];
  __shared__ float4 pl[1812];
  __shared__ float pbuf[8][2][32];
  int tid = threadIdx.x;
  int r = tid & 31, c = tid >> 5;
  int b0 = blockIdx.x * 32;
  for (int i = tid; i < 1812; i += 256) pl[i] = prm[i];
  {
    const float4* xp = (const float4*)(x + (size_t)(b0 + r) * 256 + c * 32);
#pragma unroll
    for (int j = 0; j < 8; ++j) {
      float4 g = xp[j];
      int f = c * 32 + 4 * j;
      xls[(f + 0) * 32 + (r ^ ((4 * j + 0) & 31))] = g.x;
      xls[(f + 1) * 32 + (r ^ ((4 * j + 1) & 31))] = g.y;
      xls[(f + 2) * 32 + (r ^ ((4 * j + 2) & 31))] = g.z;
      xls[(f + 3) * 32 + (r ^ ((4 * j + 3) & 31))] = g.w;
    }
  }
  __syncthreads();
  // ---- L0: group c -> features [c*32, c*32+32)
  float a0 = 0.f, a1 = 0.f;
#pragma unroll
  for (int j = 0; j < 32; ++j) {
    int f = c * 32 + j;
    float xv = xls[f * 32 + (r ^ j)];
    float4 p = pl[f];
    float e = entpair(p.x, xv);
    a0 = __builtin_fmaf(e, p.y, a0);
    a1 = __builtin_fmaf(-e, p.z, a1);
  }
  pbuf[c][0][r] = a0;
  pbuf[c][1][r] = a1;
  __syncthreads();
  float xe1[2];
#pragma unroll
  for (int o = 0; o < 2; ++o) {
    float v = cstf[o];
#pragma unroll
    for (int k = 0; k < 8; ++k) v += pbuf[k][o][r];
    xe1[o] = v;
  }
  __syncthreads();
  // ---- L1: stump c>>2, feature slice (c&3)*64; extras on slice 0
  {
    int s = c >> 2, fs = c & 3;
    const float4* ps = &pl[256 + s * 258];
    a0 = 0.f;
    a1 = 0.f;
#pragma unroll
    for (int j = 0; j < 64; ++j) {
      int f = fs * 64 + j;
      float xv = xls[f * 32 + (r ^ (f & 31))];
      float4 p = ps[f];
      float e = entpair(p.x, xv);
      a0 = __builtin_fmaf(e, p.y, a0);
      a1 = __builtin_fmaf(-e, p.z, a1);
    }
    if (fs == 0) {
#pragma unroll
      for (int o = 0; o < 2; ++o) {
        float4 p = ps[256 + o];
        float e = entpair(p.x, xe1[o]);
        a0 = __builtin_fmaf(e, p.y, a0);
        a1 = __builtin_fmaf(-e, p.z, a1);
      }
    }
    pbuf[c][0][r] = a0;
    pbuf[c][1][r] = a1;
  }
  __syncthreads();
  float xe2[4];
#pragma unroll
  for (int s = 0; s < 2; ++s)
#pragma unroll
    for (int o = 0; o < 2; ++o) {
      float v = cstf[2 + 2 * s + o];
#pragma unroll
      for (int k = 0; k < 4; ++k) v += pbuf[4 * s + k][o][r];
      xe2[2 * s + o] = v;
    }
  __syncthreads();
  // ---- L2: stump c>>1, feature slice (c&1)*128; extras on slice 0
  {
    int s = c >> 1, fs = c & 1;
    const float4* ps = &pl[772 + s * 260];
    a0 = 0.f;
    a1 = 0.f;
#pragma unroll
    for (int j = 0; j < 128; ++j) {
      int f = fs * 128 + j;
      float xv = xls[f * 32 + (r ^ (f & 31))];
      float4 p = ps[f];
      float e = entpair(p.x, xv);
      a0 = __builtin_fmaf(e, p.y, a0);
      a1 = __builtin_fmaf(-e, p.z, a1);
    }
    if (fs == 0) {
#pragma unroll
      for (int o = 0; o < 4; ++o) {
        float4 p = ps[256 + o];
        float e = entpair(p.x, xe2[o]);
        a0 = __builtin_fmaf(e, p.y, a0);
        a1 = __builtin_fmaf(-e, p.z, a1);
      }
    }
    pbuf[c][0][r] = a0;
    pbuf[c][1][r] = a1;
  }
  __syncthreads();
  // ---- reduce L2 -> out2T[4c+i][b0+r]
  if (c < 2) {
#pragma unroll
    for (int i = 0; i < 4; ++i) {
      int s = 2 * c + (i >> 1), o = i & 1;
      float v = cstf[6 + 2 * s + o];
#pragma unroll
      for (int k = 0; k < 2; ++k) v += pbuf[2 * s + k][o][r];
      out2T[(size_t)(4 * c + i) * SP + b0 + r] = v;
    }
  }
}

// ---------------- big levels (3,4,5): feature-major, lane <-> column, 2-way f-split --
// Block = 512 thr: group fh (0/1) of 256 threads handles features [fh*128,(fh+1)*128);
// group 1 also does the EX prev-level features. Partials combine via 2KB LDS.
// xT/prevT have padded stride SP (channel decorrelation). Params in LDS broadcast.
// Grid (32 colblks, nstumps): one stump per block.
template <int EX, bool FINAL>
__global__ __launch_bounds__(512, 4) void ndt_bigT(const float* __restrict__ xT,
                                                   const float* __restrict__ prevT,
                                                   const float4* __restrict__ prmL,
                                                   const float* __restrict__ cstL,
                                                   float* __restrict__ outp) {
  constexpr int FD = 256 + EX;
  __shared__ float4 pl[FD];
  __shared__ float2 pb[256];
  int tid = threadIdx.x;
  int lcol = tid & 255, fh = tid >> 8;
  int s = blockIdx.y;
  for (int i = tid; i < FD; i += 512) pl[i] = prmL[(size_t)s * FD + i];
  __syncthreads();

  int col = blockIdx.x * 256 + lcol;
  float a0 = 0.f, a1 = 0.f;
  const float* xc = xT + (size_t)(fh * 128) * SP + col;
#pragma unroll 8
  for (int f = 0; f < 128; ++f) {
    float xv = xc[(size_t)f * SP];
    float4 p = pl[fh * 128 + f];  // wave-uniform -> LDS broadcast
    float e = entpair(p.x, xv);
    a0 = __builtin_fmaf(e, p.y, a0);
    a1 = __builtin_fmaf(-e, p.z, a1);
  }
  if (fh == 1) {
    const float* pc = prevT + col;
#pragma unroll
    for (int o = 0; o < EX; ++o) {
      float pv = pc[(size_t)o * SP];
      float4 p = pl[256 + o];
      float e = entpair(p.x, pv);
      a0 = __builtin_fmaf(e, p.y, a0);
      a1 = __builtin_fmaf(-e, p.z, a1);
    }
    pb[lcol] = make_float2(a0, a1);
  }
  __syncthreads();
  if (fh == 0) {
    float2 t = pb[lcol];
    float r0 = a0 + t.x + cstL[2 * s];
    float r1 = a1 + t.y + cstL[2 * s + 1];
    if (FINAL) {
      *(float2*)(outp + (size_t)col * 64 + 2 * s) = make_float2(r0, r1);
    } else {
      outp[(size_t)(2 * s) * SP + col] = r0;
      outp[(size_t)(2 * s + 1) * SP + col] = r1;
    }
  }
}

extern "C" void kernel_launch(void* const* d_in, const int* in_sizes, int n_in,
                              void* d_out, int out_size, void* d_ws, size_t ws_size,
                              hipStream_t stream) {
  const float* x = (const float*)d_in[0];
  float* out = (float*)d_out;
  float* wsf = (float*)d_ws;

  // ws layout (float offsets), padded stride SP
  float* xT = wsf + 0;                     // [256][SP]
  float* out2T = wsf + 2113536;            // [8][SP]
  float* out3T = wsf + 2179584;            // [16][SP]
  float* out4T = wsf + 2311680;            // [32][SP]
  float4* prm = (float4*)(wsf + 2575872);  // 17492 float4
  float* cstf = wsf + 2645840;             // 126 floats

  hipLaunchKernelGGL(ndt_transpose, dim3(8, B_SZ / 32), dim3(32, 8), 0, stream,
                     x, xT);

  MaskArgs ma;
  for (int d = 0; d < 6; ++d) {
    ma.fm[d] = (const float*)d_in[1 + 3 * d];
    ma.cp[d] = (const float*)d_in[2 + 3 * d];
    ma.lr[d] = (const float*)d_in[3 + 3 * d];
  }
  ma.out_masks = out;
  ma.prm = prm;
  ma.cstf = cstf;
  hipLaunchKernelGGL(ndt_masks, dim3(63), dim3(64), 0, stream, ma);

  // levels 0-2 fused (row-major x; writes out2T transposed, padded)
  hipLaunchKernelGGL(ndt_l012, dim3(B_SZ / 32), dim3(256), 0, stream,
                     x, prm, cstf, out2T);
  // level 3: 8 stumps; grid (32, 8), 512-thr 2-way f-split
  hipLaunchKernelGGL((ndt_bigT<8, false>), dim3(32, 8), dim3(512), 0, stream,
                     xT, out2T, prm + 1812, cstf + 14, out3T);
  // level 4: 16 stumps; grid (32, 16)
  hipLaunchKernelGGL((ndt_bigT<16, false>), dim3(32, 16), dim3(512), 0, stream,
                     xT, out3T, prm + 3924, cstf + 30, out4T);
  // level 5: 32 stumps; grid (32, 32), final row-major write
  hipLaunchKernelGGL((ndt_bigT<32, true>), dim3(32, 32), dim3(512), 0, stream,
                     xT, out4T, prm + 8276, cstf + 62, out);
}